// Round 4
// baseline (1394.775 us; speedup 1.0000x reference)
//
#include <hip/hip_runtime.h>
#include <math.h>

#define B_  32
#define S_  1024
#define D_  256
#define DS_ 64
#define M_  3
#define MD_ 192   // M*DS

// lgkmcnt-only barrier: LDS visibility without draining vmcnt.
#define BAR_LGKM() asm volatile("s_waitcnt lgkmcnt(0)\n\ts_barrier" ::: "memory")

__device__ __forceinline__ float rl_f32(float v, int lane) {
    return __uint_as_float(__builtin_amdgcn_readlane(__float_as_uint(v), lane));
}

#define L2E_ 1.4426950408889634f
__device__ __forceinline__ float fast_exp(float x) { return exp2f(x * L2E_); }
__device__ __forceinline__ float fast_tanh(float x) {
    float t = exp2f(x * (2.0f * L2E_));
    return 1.0f - 2.0f * __builtin_amdgcn_rcpf(t + 1.0f);
}

typedef float v4f __attribute__((ext_vector_type(4)));

// ---- weight block: 16 float4 loaded via ASM so they are NOT rematerializable
#define ALD4(dst, p, off) \
    asm volatile("global_load_dwordx4 %0, %1, off offset:" #off \
                 : "=v"(dst) : "v"(p))

#define DECL_WSET(P, baseptr) \
    v4f P##00, P##01, P##02, P##03, P##04, P##05, P##06, P##07, \
        P##08, P##09, P##10, P##11, P##12, P##13, P##14, P##15; \
    { const float* _wp = (baseptr); \
      ALD4(P##00, _wp, 0);   ALD4(P##01, _wp, 16);  ALD4(P##02, _wp, 32);  ALD4(P##03, _wp, 48);  \
      ALD4(P##04, _wp, 64);  ALD4(P##05, _wp, 80);  ALD4(P##06, _wp, 96);  ALD4(P##07, _wp, 112); \
      ALD4(P##08, _wp, 128); ALD4(P##09, _wp, 144); ALD4(P##10, _wp, 160); ALD4(P##11, _wp, 176); \
      ALD4(P##12, _wp, 192); ALD4(P##13, _wp, 208); ALD4(P##14, _wp, 224); ALD4(P##15, _wp, 240); \
      asm volatile("s_waitcnt vmcnt(0)" ::: "memory"); }

#define EFMA __builtin_elementwise_fma

// single 64-dot against weight set W (k1/k3)
#define DOT64_PKV(h4, out) { \
    v4f A0 = W00 * (h4)[0]; \
    v4f A1 = W01 * (h4)[1]; \
    v4f A2 = W02 * (h4)[2]; \
    v4f A3 = W03 * (h4)[3]; \
    A0 = EFMA(W04, (h4)[4],  A0); \
    A1 = EFMA(W05, (h4)[5],  A1); \
    A2 = EFMA(W06, (h4)[6],  A2); \
    A3 = EFMA(W07, (h4)[7],  A3); \
    A0 = EFMA(W08, (h4)[8],  A0); \
    A1 = EFMA(W09, (h4)[9],  A1); \
    A2 = EFMA(W10, (h4)[10], A2); \
    A3 = EFMA(W11, (h4)[11], A3); \
    A0 = EFMA(W12, (h4)[12], A0); \
    A1 = EFMA(W13, (h4)[13], A1); \
    A2 = EFMA(W14, (h4)[14], A2); \
    A3 = EFMA(W15, (h4)[15], A3); \
    v4f T = (A0 + A1) + (A2 + A3); \
    out = (T.x + T.y) + (T.z + T.w); \
}

// ---- DPP full-wave sum reduce; result lane 63.
#define DPP_RED3(A, Bv, C) asm volatile( \
    "v_add_f32 %0, %0, %0 row_shr:1 bound_ctrl:0\n\t" \
    "v_add_f32 %1, %1, %1 row_shr:1 bound_ctrl:0\n\t" \
    "v_add_f32 %2, %2, %2 row_shr:1 bound_ctrl:0\n\t" \
    "v_add_f32 %0, %0, %0 row_shr:2 bound_ctrl:0\n\t" \
    "v_add_f32 %1, %1, %1 row_shr:2 bound_ctrl:0\n\t" \
    "v_add_f32 %2, %2, %2 row_shr:2 bound_ctrl:0\n\t" \
    "v_add_f32 %0, %0, %0 row_shr:4 bound_ctrl:0\n\t" \
    "v_add_f32 %1, %1, %1 row_shr:4 bound_ctrl:0\n\t" \
    "v_add_f32 %2, %2, %2 row_shr:4 bound_ctrl:0\n\t" \
    "v_add_f32 %0, %0, %0 row_shr:8 bound_ctrl:0\n\t" \
    "v_add_f32 %1, %1, %1 row_shr:8 bound_ctrl:0\n\t" \
    "v_add_f32 %2, %2, %2 row_shr:8 bound_ctrl:0\n\t" \
    "v_add_f32 %0, %0, %0 row_bcast:15 row_mask:0xa\n\t" \
    "v_add_f32 %1, %1, %1 row_bcast:15 row_mask:0xa\n\t" \
    "v_add_f32 %2, %2, %2 row_bcast:15 row_mask:0xa\n\t" \
    "v_add_f32 %0, %0, %0 row_bcast:31 row_mask:0xc\n\t" \
    "v_add_f32 %1, %1, %1 row_bcast:31 row_mask:0xc\n\t" \
    "v_add_f32 %2, %2, %2 row_bcast:31 row_mask:0xc" \
    : "+v"(A), "+v"(Bv), "+v"(C))

#define DPP_RED4(A, Bv, C, Dv) asm volatile( \
    "v_add_f32 %0, %0, %0 row_shr:1 bound_ctrl:0\n\t" \
    "v_add_f32 %1, %1, %1 row_shr:1 bound_ctrl:0\n\t" \
    "v_add_f32 %2, %2, %2 row_shr:1 bound_ctrl:0\n\t" \
    "v_add_f32 %3, %3, %3 row_shr:1 bound_ctrl:0\n\t" \
    "v_add_f32 %0, %0, %0 row_shr:2 bound_ctrl:0\n\t" \
    "v_add_f32 %1, %1, %1 row_shr:2 bound_ctrl:0\n\t" \
    "v_add_f32 %2, %2, %2 row_shr:2 bound_ctrl:0\n\t" \
    "v_add_f32 %3, %3, %3 row_shr:2 bound_ctrl:0\n\t" \
    "v_add_f32 %0, %0, %0 row_shr:4 bound_ctrl:0\n\t" \
    "v_add_f32 %1, %1, %1 row_shr:4 bound_ctrl:0\n\t" \
    "v_add_f32 %2, %2, %2 row_shr:4 bound_ctrl:0\n\t" \
    "v_add_f32 %3, %3, %3 row_shr:4 bound_ctrl:0\n\t" \
    "v_add_f32 %0, %0, %0 row_shr:8 bound_ctrl:0\n\t" \
    "v_add_f32 %1, %1, %1 row_shr:8 bound_ctrl:0\n\t" \
    "v_add_f32 %2, %2, %2 row_shr:8 bound_ctrl:0\n\t" \
    "v_add_f32 %3, %3, %3 row_shr:8 bound_ctrl:0\n\t" \
    "v_add_f32 %0, %0, %0 row_bcast:15 row_mask:0xa\n\t" \
    "v_add_f32 %1, %1, %1 row_bcast:15 row_mask:0xa\n\t" \
    "v_add_f32 %2, %2, %2 row_bcast:15 row_mask:0xa\n\t" \
    "v_add_f32 %3, %3, %3 row_bcast:15 row_mask:0xa\n\t" \
    "v_add_f32 %0, %0, %0 row_bcast:31 row_mask:0xc\n\t" \
    "v_add_f32 %1, %1, %1 row_bcast:31 row_mask:0xc\n\t" \
    "v_add_f32 %2, %2, %2 row_bcast:31 row_mask:0xc\n\t" \
    "v_add_f32 %3, %3, %3 row_bcast:31 row_mask:0xc" \
    : "+v"(A), "+v"(Bv), "+v"(C), "+v"(Dv))

// ---------------------------------------------------------------------------
// Kernel 1: xp[b][t][m*64+d] = Xb[m][d] + sum_k XW[m][d][k] * x_m[b][t][k]
// ---------------------------------------------------------------------------
__global__ __launch_bounds__(256, 2)
void k1_xproj(const float* __restrict__ xa, const float* __restrict__ xv,
              const float* __restrict__ xl, const float* __restrict__ XW,
              const float* __restrict__ Xb, float* __restrict__ xp)
{
    const int m  = blockIdx.z;
    const int b  = blockIdx.y;
    const int t0 = blockIdx.x * 128;
    const float* __restrict__ xm = (m == 0) ? xa : ((m == 1) ? xv : xl);
    const int tid = threadIdx.x;
    const int q = tid >> 6;
    const int d = tid & 63;

    __shared__ __align__(16) float xs[1024];
    __shared__ float part[4][4][64];

    DECL_WSET(W, XW + ((m * 64 + d) * 256 + q * 64));
    const float xbv = Xb[m * 64 + d];

    for (int g = 0; g < 32; ++g) {
        const int tb = t0 + g * 4;
        reinterpret_cast<v4f*>(xs)[tid] =
            reinterpret_cast<const v4f*>(xm + ((size_t)b * S_ + tb) * D_)[tid];
        __syncthreads();
        #pragma unroll
        for (int tt = 0; tt < 4; ++tt) {
            const v4f* xq = reinterpret_cast<const v4f*>(&xs[tt * 256 + q * 64]);
            float accv;
            DOT64_PKV(xq, accv);
            part[tt][q][d] = accv;
        }
        __syncthreads();
        {
            const int tt = q;
            float ssum = part[tt][0][d] + part[tt][1][d] + part[tt][2][d] + part[tt][3][d] + xbv;
            xp[((size_t)b * S_ + tb + tt) * MD_ + m * 64 + d] = ssum;
        }
    }
}

// ---------------------------------------------------------------------------
// Kernel 2 v7: recurrence. 32 blocks x 384 threads (6 waves), 2 dots/wave.
// The 4 consumers of h-segment s (su rows (0,s),(1,s),(2,s) + gate slice s)
// are packed into 2 waves; each wave loads its segment ONCE into 16 v4f regs
// (16 ds_read_b128 broadcasts) and runs TWO pk-fma dot chains against two
// asm-pinned weight sets. Halves the LDS broadcast traffic (192->96 b128 per
// step), which round-3 counters showed to be the per-CU bottleneck.
//   wave w: seg = w>>1, half = w&1.
//   half 0: dots (m=0,seg) -> parts[seg], (m=1,seg) -> parts[3+seg]
//   half 1: dots (m=2,seg) -> parts[6+seg], gate slice seg -> parts[9+seg];
//           then tail for modality m=seg (own gate slice is in-reg).
// ---------------------------------------------------------------------------
__global__ __launch_bounds__(384, 1)
void k2_recur(const float* __restrict__ xp, float* __restrict__ hbuf,
              const float* __restrict__ HW, const float* __restrict__ Hb,
              const float* __restrict__ CW, const float* __restrict__ W1,
              const float* __restrict__ b1, const float* __restrict__ W2,
              const float* __restrict__ b2)
{
    const int b    = blockIdx.x;
    const int tid  = threadIdx.x;
    const int w    = tid >> 6;
    const int lane = tid & 63;

    const int  seg     = w >> 1;          // h segment this wave reads
    const bool is_tail = (w & 1);         // half==1 waves own gate+tail, m=seg
    const int  m       = seg;             // tail modality (tail waves only)

    __shared__ __align__(16) float hds[2][MD_];
    __shared__ float parts[12][64];

    if (tid < MD_) hds[0][tid] = 0.f;

    // ---- two weight sets per wave, asm-pinned (non-remat) ----
    const float* baseA;
    const float* baseB;
    int rowA, rowB;
    if (!is_tail) {
        baseA = (seg == 0) ? (HW + lane * 64)
                           : (CW + ((0 * 3 + seg) * 64 + lane) * 64);
        baseB = (seg == 1) ? (HW + (64 + lane) * 64)
                           : (CW + ((1 * 3 + seg) * 64 + lane) * 64);
        rowA = seg; rowB = 3 + seg;
    } else {
        baseA = (seg == 2) ? (HW + (128 + lane) * 64)
                           : (CW + ((2 * 3 + seg) * 64 + lane) * 64);
        baseB = W1 + lane * MD_ + seg * 64;
        rowA = 6 + seg; rowB = 9 + seg;
    }
    DECL_WSET(W, baseA);
    DECL_WSET(X, baseB);

    // tail-wave constants
    float hbv = 0.f, b1v = 0.f;
    float w2r0 = 0.f, w2r1 = 0.f, w2r2 = 0.f, b2v0 = 0.f, b2v1 = 0.f, b2v2 = 0.f;
    float xnext = 0.f;
    if (is_tail) {
        hbv  = Hb[m * 64 + lane];
        b1v  = b1[lane];
        w2r0 = W2[(m * 3 + 0) * 64 + lane];
        w2r1 = W2[(m * 3 + 1) * 64 + lane];
        w2r2 = W2[(m * 3 + 2) * 64 + lane];
        b2v0 = b2[m * 3 + 0]; b2v1 = b2[m * 3 + 1]; b2v2 = b2[m * 3 + 2];
        xnext = xp[((size_t)b * S_) * MD_ + m * 64 + lane];
    }
    const int s1 = (m + 1) % 3, s2 = (m + 2) % 3;
    float hist0 = 0.f, hist1 = 0.f, hist2 = 0.f, hist3 = 0.f;

    __syncthreads();

    for (int t = 0; t < S_; ++t) {
        const int cur = t & 1, nxt = cur ^ 1;

        const float xv = xnext;
        if (is_tail && (t + 1 < S_))
            xnext = xp[((size_t)b * S_ + t + 1) * MD_ + m * 64 + lane];

        // ---- phase A: load segment once, run two dot chains ----
        const v4f* h4 = reinterpret_cast<const v4f*>(&hds[cur][seg * 64]);
        float accA, accB;
        {
            v4f A0, A1, A2, A3, B0, B1, B2, B3;
            {
                v4f H0 = h4[0], H1 = h4[1], H2 = h4[2], H3 = h4[3];
                A0 = W00 * H0; B0 = X00 * H0;
                A1 = W01 * H1; B1 = X01 * H1;
                A2 = W02 * H2; B2 = X02 * H2;
                A3 = W03 * H3; B3 = X03 * H3;
            }
            {
                v4f H0 = h4[4], H1 = h4[5], H2 = h4[6], H3 = h4[7];
                A0 = EFMA(W04, H0, A0); B0 = EFMA(X04, H0, B0);
                A1 = EFMA(W05, H1, A1); B1 = EFMA(X05, H1, B1);
                A2 = EFMA(W06, H2, A2); B2 = EFMA(X06, H2, B2);
                A3 = EFMA(W07, H3, A3); B3 = EFMA(X07, H3, B3);
            }
            {
                v4f H0 = h4[8], H1 = h4[9], H2 = h4[10], H3 = h4[11];
                A0 = EFMA(W08, H0, A0); B0 = EFMA(X08, H0, B0);
                A1 = EFMA(W09, H1, A1); B1 = EFMA(X09, H1, B1);
                A2 = EFMA(W10, H2, A2); B2 = EFMA(X10, H2, B2);
                A3 = EFMA(W11, H3, A3); B3 = EFMA(X11, H3, B3);
            }
            {
                v4f H0 = h4[12], H1 = h4[13], H2 = h4[14], H3 = h4[15];
                A0 = EFMA(W12, H0, A0); B0 = EFMA(X12, H0, B0);
                A1 = EFMA(W13, H1, A1); B1 = EFMA(X13, H1, B1);
                A2 = EFMA(W14, H2, A2); B2 = EFMA(X14, H2, B2);
                A3 = EFMA(W15, H3, A3); B3 = EFMA(X15, H3, B3);
            }
            v4f TA = (A0 + A1) + (A2 + A3);
            v4f TB = (B0 + B1) + (B2 + B3);
            accA = (TA.x + TA.y) + (TA.z + TA.w);
            accB = (TB.x + TB.y) + (TB.z + TB.w);
        }
        parts[rowA][lane] = accA;
        parts[rowB][lane] = accB;
        BAR_LGKM();   // all partials visible

        // ---- tail wave m: gate + combine + state update ----
        if (is_tail) {
            float pm  = parts[m * 3 + m][lane];
            float pc1 = parts[m * 3 + s1][lane];
            float pc2 = parts[m * 3 + s2][lane];
            float go1 = parts[9 + s1][lane];
            float go2 = parts[9 + s2][lane];

            float z = fast_tanh(b1v + accB + go1 + go2);   // accB = own gate slice
            float p0 = w2r0 * z, p1 = w2r1 * z, p2 = w2r2 * z;
            DPP_RED3(p0, p1, p2);   // 64-lane sums -> lane 63
            float r0 = b2v0 + rl_f32(p0, 63);
            float r1 = b2v1 + rl_f32(p1, 63);
            float r2 = b2v2 + rl_f32(p2, 63);
            float mx  = fmaxf(r0, fmaxf(r1, r2));
            float e0  = fast_exp(r0 - mx);
            float e1  = fast_exp(r1 - mx);
            float e2  = fast_exp(r2 - mx);
            float inv = __builtin_amdgcn_rcpf(e0 + e1 + e2);
            float a1v = ((s1 == 1) ? e1 : (s1 == 2) ? e2 : e0) * inv;
            float a2v = ((s2 == 1) ? e1 : (s2 == 2) ? e2 : e0) * inv;

            float suv = xv + hbv + pm + a1v * pc1 + a2v * pc2;
            float hn  = suv * __builtin_amdgcn_rcpf(1.f + fast_exp(-suv));
            hds[nxt][m * 64 + lane] = hn;

            if      ((t & 3) == 0) hist0 = hn;
            else if ((t & 3) == 1) hist1 = hn;
            else if ((t & 3) == 2) hist2 = hn;
            else {
                hist3 = hn;
                float* dst = hbuf + ((size_t)b * S_ + (t - 3)) * MD_ + m * 64 + lane;
                dst[0 * MD_] = hist0; dst[1 * MD_] = hist1;
                dst[2 * MD_] = hist2; dst[3 * MD_] = hist3;
            }
        }
        BAR_LGKM();   // h_new visible
    }
}

// ---------------------------------------------------------------------------
// Kernel 3: out = LayerNorm(Ob + OW@h + x); OW row asm-pinned in registers.
// ---------------------------------------------------------------------------
__global__ __launch_bounds__(256, 2)
void k3_out(const float* __restrict__ xa, const float* __restrict__ xv,
            const float* __restrict__ xl, const float* __restrict__ hbuf,
            const float* __restrict__ OW, const float* __restrict__ Ob,
            const float* __restrict__ lng, const float* __restrict__ lnb,
            float* __restrict__ out)
{
    const int m  = blockIdx.z;
    const int b  = blockIdx.y;
    const int t0 = blockIdx.x * 128;
    const float* __restrict__ xm = (m == 0) ? xa : ((m == 1) ? xv : xl);
    const int k    = threadIdx.x;
    const int wv   = k >> 6;
    const int lane = k & 63;

    __shared__ __align__(16) float hs[4 * 64];
    __shared__ float psum[16], qsum[16];

    DECL_WSET(W, OW + (m * D_ + k) * DS_);
    const float obv = Ob[m * D_ + k];
    const float gv  = lng[m * D_ + k];
    const float bv  = lnb[m * D_ + k];

    for (int gg = 0; gg < 32; ++gg) {
        const int tb = t0 + gg * 4;
        hs[k] = hbuf[((size_t)b * S_ + tb + (k >> 6)) * MD_ + m * 64 + (k & 63)];
        __syncthreads();

        float v0, v1, v2, v3;
        {
            const v4f* h4 = reinterpret_cast<const v4f*>(&hs[0]);
            float accv; DOT64_PKV(h4, accv);
            v0 = obv + accv + xm[((size_t)b * S_ + tb + 0) * D_ + k];
        }
        {
            const v4f* h4 = reinterpret_cast<const v4f*>(&hs[64]);
            float accv; DOT64_PKV(h4, accv);
            v1 = obv + accv + xm[((size_t)b * S_ + tb + 1) * D_ + k];
        }
        {
            const v4f* h4 = reinterpret_cast<const v4f*>(&hs[128]);
            float accv; DOT64_PKV(h4, accv);
            v2 = obv + accv + xm[((size_t)b * S_ + tb + 2) * D_ + k];
        }
        {
            const v4f* h4 = reinterpret_cast<const v4f*>(&hs[192]);
            float accv; DOT64_PKV(h4, accv);
            v3 = obv + accv + xm[((size_t)b * S_ + tb + 3) * D_ + k];
        }

        float s0 = v0, s1v = v1, s2v = v2, s3 = v3;
        float q0 = v0 * v0, q1 = v1 * v1, q2 = v2 * v2, q3 = v3 * v3;
        DPP_RED4(s0, s1v, s2v, s3);
        DPP_RED4(q0, q1, q2, q3);
        if (lane == 63) {
            psum[wv * 4 + 0] = s0;  psum[wv * 4 + 1] = s1v;
            psum[wv * 4 + 2] = s2v; psum[wv * 4 + 3] = s3;
            qsum[wv * 4 + 0] = q0;  qsum[wv * 4 + 1] = q1;
            qsum[wv * 4 + 2] = q2;  qsum[wv * 4 + 3] = q3;
        }
        __syncthreads();

        const size_t obase = (size_t)m * ((size_t)B_ * S_ * D_) + ((size_t)b * S_ + tb) * D_ + k;
        {
            float ss = psum[0] + psum[4] + psum[8] + psum[12];
            float qq = qsum[0] + qsum[4] + qsum[8] + qsum[12];
            float mu = ss * (1.f / 256.f);
            float var = qq * (1.f / 256.f) - mu * mu;
            float rs = rsqrtf(var + 1e-5f);
            out[obase + 0 * D_] = (v0 - mu) * rs * gv + bv;
        }
        {
            float ss = psum[1] + psum[5] + psum[9] + psum[13];
            float qq = qsum[1] + qsum[5] + qsum[9] + qsum[13];
            float mu = ss * (1.f / 256.f);
            float var = qq * (1.f / 256.f) - mu * mu;
            float rs = rsqrtf(var + 1e-5f);
            out[obase + 1 * D_] = (v1 - mu) * rs * gv + bv;
        }
        {
            float ss = psum[2] + psum[6] + psum[10] + psum[14];
            float qq = qsum[2] + qsum[6] + qsum[10] + qsum[14];
            float mu = ss * (1.f / 256.f);
            float var = qq * (1.f / 256.f) - mu * mu;
            float rs = rsqrtf(var + 1e-5f);
            out[obase + 2 * D_] = (v2 - mu) * rs * gv + bv;
        }
        {
            float ss = psum[3] + psum[7] + psum[11] + psum[15];
            float qq = qsum[3] + qsum[7] + qsum[11] + qsum[15];
            float mu = ss * (1.f / 256.f);
            float var = qq * (1.f / 256.f) - mu * mu;
            float rs = rsqrtf(var + 1e-5f);
            out[obase + 3 * D_] = (v3 - mu) * rs * gv + bv;
        }
    }
}

extern "C" void kernel_launch(void* const* d_in, const int* in_sizes, int n_in,
                              void* d_out, int out_size, void* d_ws, size_t ws_size,
                              hipStream_t stream)
{
    const float* xa  = (const float*)d_in[0];
    const float* xv  = (const float*)d_in[1];
    const float* xl  = (const float*)d_in[2];
    const float* XW  = (const float*)d_in[3];
    const float* Xb  = (const float*)d_in[4];
    const float* HW  = (const float*)d_in[5];
    const float* Hb  = (const float*)d_in[6];
    const float* OW  = (const float*)d_in[7];
    const float* Ob  = (const float*)d_in[8];
    const float* CW  = (const float*)d_in[9];
    const float* W1  = (const float*)d_in[10];
    const float* b1  = (const float*)d_in[11];
    const float* W2  = (const float*)d_in[12];
    const float* b2  = (const float*)d_in[13];
    const float* lng = (const float*)d_in[14];
    const float* lnb = (const float*)d_in[15];
    float* out = (float*)d_out;

    float* xp = (float*)d_ws;                          // [B][S][192]
    float* hb = xp + (size_t)B_ * S_ * MD_;            // [B][S][192]

    k1_xproj<<<dim3(8, 32, 3), 256, 0, stream>>>(xa, xv, xl, XW, Xb, xp);
    k2_recur<<<dim3(32), 384, 0, stream>>>(xp, hb, HW, Hb, CW, W1, b1, W2, b2);
    k3_out  <<<dim3(8, 32, 3), 256, 0, stream>>>(xa, xv, xl, hb, OW, Ob, lng, lnb, out);
}

// Round 5
// 1312.238 us; speedup vs baseline: 1.0629x; 1.0629x over previous
//
#include <hip/hip_runtime.h>
#include <math.h>

#define B_  32
#define S_  1024
#define D_  256
#define DS_ 64
#define M_  3
#define MD_ 192   // M*DS

// lgkmcnt-only barrier: LDS visibility without draining vmcnt.
#define BAR_LGKM() asm volatile("s_waitcnt lgkmcnt(0)\n\ts_barrier" ::: "memory")

__device__ __forceinline__ float rl_f32(float v, int lane) {
    return __uint_as_float(__builtin_amdgcn_readlane(__float_as_uint(v), lane));
}

#define L2E_ 1.4426950408889634f
__device__ __forceinline__ float fast_exp(float x) { return exp2f(x * L2E_); }
__device__ __forceinline__ float fast_tanh(float x) {
    float t = exp2f(x * (2.0f * L2E_));
    return 1.0f - 2.0f * __builtin_amdgcn_rcpf(t + 1.0f);
}

typedef float v4f __attribute__((ext_vector_type(4)));

// ---- asm loads: non-rematerializable, so weights stay register-resident.
#define ALD4(dst, p, off) \
    asm volatile("global_load_dwordx4 %0, %1, off offset:" #off \
                 : "=v"(dst) : "v"(p))

// 16 x float4 = full 64-float row (k1/k3)
#define DECL_WSET(P, baseptr) \
    v4f P##00, P##01, P##02, P##03, P##04, P##05, P##06, P##07, \
        P##08, P##09, P##10, P##11, P##12, P##13, P##14, P##15; \
    { const float* _wp = (baseptr); \
      ALD4(P##00, _wp, 0);   ALD4(P##01, _wp, 16);  ALD4(P##02, _wp, 32);  ALD4(P##03, _wp, 48);  \
      ALD4(P##04, _wp, 64);  ALD4(P##05, _wp, 80);  ALD4(P##06, _wp, 96);  ALD4(P##07, _wp, 112); \
      ALD4(P##08, _wp, 128); ALD4(P##09, _wp, 144); ALD4(P##10, _wp, 160); ALD4(P##11, _wp, 176); \
      ALD4(P##12, _wp, 192); ALD4(P##13, _wp, 208); ALD4(P##14, _wp, 224); ALD4(P##15, _wp, 240); \
      asm volatile("s_waitcnt vmcnt(0)" ::: "memory"); }

// 8 x float4 = 32-float half-row (k2 half-dots)
#define DECL_WSET8(P, baseptr) \
    v4f P##0, P##1, P##2, P##3, P##4, P##5, P##6, P##7; \
    { const float* _wp = (baseptr); \
      ALD4(P##0, _wp, 0);  ALD4(P##1, _wp, 16); ALD4(P##2, _wp, 32); ALD4(P##3, _wp, 48); \
      ALD4(P##4, _wp, 64); ALD4(P##5, _wp, 80); ALD4(P##6, _wp, 96); ALD4(P##7, _wp, 112); \
      asm volatile("s_waitcnt vmcnt(0)" ::: "memory"); }

#define EFMA __builtin_elementwise_fma

// single 64-dot against weight set W (k1/k3)
#define DOT64_PKV(h4, out) { \
    v4f A0 = W00 * (h4)[0]; \
    v4f A1 = W01 * (h4)[1]; \
    v4f A2 = W02 * (h4)[2]; \
    v4f A3 = W03 * (h4)[3]; \
    A0 = EFMA(W04, (h4)[4],  A0); \
    A1 = EFMA(W05, (h4)[5],  A1); \
    A2 = EFMA(W06, (h4)[6],  A2); \
    A3 = EFMA(W07, (h4)[7],  A3); \
    A0 = EFMA(W08, (h4)[8],  A0); \
    A1 = EFMA(W09, (h4)[9],  A1); \
    A2 = EFMA(W10, (h4)[10], A2); \
    A3 = EFMA(W11, (h4)[11], A3); \
    A0 = EFMA(W12, (h4)[12], A0); \
    A1 = EFMA(W13, (h4)[13], A1); \
    A2 = EFMA(W14, (h4)[14], A2); \
    A3 = EFMA(W15, (h4)[15], A3); \
    v4f T = (A0 + A1) + (A2 + A3); \
    out = (T.x + T.y) + (T.z + T.w); \
}

// ---- DPP full-wave sum reduce; result lane 63.
#define DPP_RED3(A, Bv, C) asm volatile( \
    "v_add_f32 %0, %0, %0 row_shr:1 bound_ctrl:0\n\t" \
    "v_add_f32 %1, %1, %1 row_shr:1 bound_ctrl:0\n\t" \
    "v_add_f32 %2, %2, %2 row_shr:1 bound_ctrl:0\n\t" \
    "v_add_f32 %0, %0, %0 row_shr:2 bound_ctrl:0\n\t" \
    "v_add_f32 %1, %1, %1 row_shr:2 bound_ctrl:0\n\t" \
    "v_add_f32 %2, %2, %2 row_shr:2 bound_ctrl:0\n\t" \
    "v_add_f32 %0, %0, %0 row_shr:4 bound_ctrl:0\n\t" \
    "v_add_f32 %1, %1, %1 row_shr:4 bound_ctrl:0\n\t" \
    "v_add_f32 %2, %2, %2 row_shr:4 bound_ctrl:0\n\t" \
    "v_add_f32 %0, %0, %0 row_shr:8 bound_ctrl:0\n\t" \
    "v_add_f32 %1, %1, %1 row_shr:8 bound_ctrl:0\n\t" \
    "v_add_f32 %2, %2, %2 row_shr:8 bound_ctrl:0\n\t" \
    "v_add_f32 %0, %0, %0 row_bcast:15 row_mask:0xa\n\t" \
    "v_add_f32 %1, %1, %1 row_bcast:15 row_mask:0xa\n\t" \
    "v_add_f32 %2, %2, %2 row_bcast:15 row_mask:0xa\n\t" \
    "v_add_f32 %0, %0, %0 row_bcast:31 row_mask:0xc\n\t" \
    "v_add_f32 %1, %1, %1 row_bcast:31 row_mask:0xc\n\t" \
    "v_add_f32 %2, %2, %2 row_bcast:31 row_mask:0xc" \
    : "+v"(A), "+v"(Bv), "+v"(C))

#define DPP_RED4(A, Bv, C, Dv) asm volatile( \
    "v_add_f32 %0, %0, %0 row_shr:1 bound_ctrl:0\n\t" \
    "v_add_f32 %1, %1, %1 row_shr:1 bound_ctrl:0\n\t" \
    "v_add_f32 %2, %2, %2 row_shr:1 bound_ctrl:0\n\t" \
    "v_add_f32 %3, %3, %3 row_shr:1 bound_ctrl:0\n\t" \
    "v_add_f32 %0, %0, %0 row_shr:2 bound_ctrl:0\n\t" \
    "v_add_f32 %1, %1, %1 row_shr:2 bound_ctrl:0\n\t" \
    "v_add_f32 %2, %2, %2 row_shr:2 bound_ctrl:0\n\t" \
    "v_add_f32 %3, %3, %3 row_shr:2 bound_ctrl:0\n\t" \
    "v_add_f32 %0, %0, %0 row_shr:4 bound_ctrl:0\n\t" \
    "v_add_f32 %1, %1, %1 row_shr:4 bound_ctrl:0\n\t" \
    "v_add_f32 %2, %2, %2 row_shr:4 bound_ctrl:0\n\t" \
    "v_add_f32 %3, %3, %3 row_shr:4 bound_ctrl:0\n\t" \
    "v_add_f32 %0, %0, %0 row_shr:8 bound_ctrl:0\n\t" \
    "v_add_f32 %1, %1, %1 row_shr:8 bound_ctrl:0\n\t" \
    "v_add_f32 %2, %2, %2 row_shr:8 bound_ctrl:0\n\t" \
    "v_add_f32 %3, %3, %3 row_shr:8 bound_ctrl:0\n\t" \
    "v_add_f32 %0, %0, %0 row_bcast:15 row_mask:0xa\n\t" \
    "v_add_f32 %1, %1, %1 row_bcast:15 row_mask:0xa\n\t" \
    "v_add_f32 %2, %2, %2 row_bcast:15 row_mask:0xa\n\t" \
    "v_add_f32 %3, %3, %3 row_bcast:15 row_mask:0xa\n\t" \
    "v_add_f32 %0, %0, %0 row_bcast:31 row_mask:0xc\n\t" \
    "v_add_f32 %1, %1, %1 row_bcast:31 row_mask:0xc\n\t" \
    "v_add_f32 %2, %2, %2 row_bcast:31 row_mask:0xc\n\t" \
    "v_add_f32 %3, %3, %3 row_bcast:31 row_mask:0xc" \
    : "+v"(A), "+v"(Bv), "+v"(C), "+v"(Dv))

// ---------------------------------------------------------------------------
// Kernel 1: xp[b][t][m*64+d] = Xb[m][d] + sum_k XW[m][d][k] * x_m[b][t][k]
// ---------------------------------------------------------------------------
__global__ __launch_bounds__(256, 2)
void k1_xproj(const float* __restrict__ xa, const float* __restrict__ xv,
              const float* __restrict__ xl, const float* __restrict__ XW,
              const float* __restrict__ Xb, float* __restrict__ xp)
{
    const int m  = blockIdx.z;
    const int b  = blockIdx.y;
    const int t0 = blockIdx.x * 128;
    const float* __restrict__ xm = (m == 0) ? xa : ((m == 1) ? xv : xl);
    const int tid = threadIdx.x;
    const int q = tid >> 6;
    const int d = tid & 63;

    __shared__ __align__(16) float xs[1024];
    __shared__ float part[4][4][64];

    DECL_WSET(W, XW + ((m * 64 + d) * 256 + q * 64));
    const float xbv = Xb[m * 64 + d];

    for (int g = 0; g < 32; ++g) {
        const int tb = t0 + g * 4;
        reinterpret_cast<v4f*>(xs)[tid] =
            reinterpret_cast<const v4f*>(xm + ((size_t)b * S_ + tb) * D_)[tid];
        __syncthreads();
        #pragma unroll
        for (int tt = 0; tt < 4; ++tt) {
            const v4f* xq = reinterpret_cast<const v4f*>(&xs[tt * 256 + q * 64]);
            float accv;
            DOT64_PKV(xq, accv);
            part[tt][q][d] = accv;
        }
        __syncthreads();
        {
            const int tt = q;
            float ssum = part[tt][0][d] + part[tt][1][d] + part[tt][2][d] + part[tt][3][d] + xbv;
            xp[((size_t)b * S_ + tb + tt) * MD_ + m * 64 + d] = ssum;
        }
    }
}

// ---------------------------------------------------------------------------
// Kernel 2 v8: recurrence. 32 blocks x 768 threads (12 waves).
// Half-dot split: each 64-deep dot is split into two 32-deep half-dots along
// k. Wave w: seg = w>>2, rem = w&3, hh = rem>>1 (which k-half), which = rem&1.
//   which=0: su (m=0,seg) and (m=1,seg) half-dots
//   which=1: su (m=2,seg) and gate-slice seg half-dots
// Each wave reads ONLY 8 ds_read_b128 (its 128B half-segment) -> block LDS
// broadcast traffic halves (192->96 b128/step), and the weight budget stays
// at r3's 16 v4f (no r4-style spill). parts[12][2][64]; tail sums halves.
// Tail waves (w0,w5,w10 -> SIMDs 0,1,2) own modality m and do gate+combine.
// xp prefetch distance = 2 to ride out L2 latency.
// ---------------------------------------------------------------------------
__global__ __launch_bounds__(768, 1)
void k2_recur(const float* __restrict__ xp, float* __restrict__ hbuf,
              const float* __restrict__ HW, const float* __restrict__ Hb,
              const float* __restrict__ CW, const float* __restrict__ W1,
              const float* __restrict__ b1, const float* __restrict__ W2,
              const float* __restrict__ b2)
{
    const int b    = blockIdx.x;
    const int tid  = threadIdx.x;
    const int w    = tid >> 6;
    const int lane = tid & 63;

    const int seg   = w >> 2;        // h segment (0..2)
    const int rem   = w & 3;
    const int hh    = rem >> 1;      // k-half (0..1)
    const int which = rem & 1;       // 0: su m0,m1; 1: su m2 + gate

    const bool is_tail = (w == 0) | (w == 5) | (w == 10);
    const int  mm      = (w == 0) ? 0 : ((w == 5) ? 1 : 2);  // tail modality

    __shared__ __align__(16) float hds[2][MD_];
    __shared__ float parts[12][2][64];

    if (tid < MD_) hds[0][tid] = 0.f;

    // ---- two half-weight sets per wave (8 v4f each = 64 floats total) ----
    const float* baseA;
    const float* baseB;
    int rowA, rowB;
    if (which == 0) {
        baseA = ((seg == 0) ? (HW + lane * 64)
                            : (CW + ((0 * 3 + seg) * 64 + lane) * 64)) + hh * 32;
        baseB = ((seg == 1) ? (HW + (64 + lane) * 64)
                            : (CW + ((1 * 3 + seg) * 64 + lane) * 64)) + hh * 32;
        rowA = 0 * 3 + seg; rowB = 1 * 3 + seg;
    } else {
        baseA = ((seg == 2) ? (HW + (128 + lane) * 64)
                            : (CW + ((2 * 3 + seg) * 64 + lane) * 64)) + hh * 32;
        baseB = W1 + lane * MD_ + seg * 64 + hh * 32;
        rowA = 2 * 3 + seg; rowB = 9 + seg;
    }
    DECL_WSET8(WA, baseA);
    DECL_WSET8(WB, baseB);

    // tail-wave constants
    float hbv = 0.f, b1v = 0.f;
    float w2r0 = 0.f, w2r1 = 0.f, w2r2 = 0.f, b2v0 = 0.f, b2v1 = 0.f, b2v2 = 0.f;
    float xn0 = 0.f, xn1 = 0.f;
    if (is_tail) {
        hbv  = Hb[mm * 64 + lane];
        b1v  = b1[lane];
        w2r0 = W2[(mm * 3 + 0) * 64 + lane];
        w2r1 = W2[(mm * 3 + 1) * 64 + lane];
        w2r2 = W2[(mm * 3 + 2) * 64 + lane];
        b2v0 = b2[mm * 3 + 0]; b2v1 = b2[mm * 3 + 1]; b2v2 = b2[mm * 3 + 2];
        xn0 = xp[((size_t)b * S_ + 0) * MD_ + mm * 64 + lane];
        xn1 = xp[((size_t)b * S_ + 1) * MD_ + mm * 64 + lane];
    }
    const int s1 = (mm + 1) % 3, s2 = (mm + 2) % 3;
    float hist0 = 0.f, hist1 = 0.f, hist2 = 0.f, hist3 = 0.f;

    __syncthreads();

    for (int t = 0; t < S_; ++t) {
        const int cur = t & 1, nxt = cur ^ 1;

        const float xv = xn0;
        xn0 = xn1;
        if (is_tail && (t + 2 < S_))
            xn1 = xp[((size_t)b * S_ + t + 2) * MD_ + mm * 64 + lane];

        // ---- phase A: 8 broadcast b128 reads, two 32-deep half-dots ----
        {
            const v4f* h4 = reinterpret_cast<const v4f*>(&hds[cur][seg * 64 + hh * 32]);
            v4f H0 = h4[0], H1 = h4[1], H2 = h4[2], H3 = h4[3];
            v4f H4 = h4[4], H5 = h4[5], H6 = h4[6], H7 = h4[7];
            v4f A0 = WA0 * H0, A1 = WA1 * H1;
            v4f B0 = WB0 * H0, B1 = WB1 * H1;
            A0 = EFMA(WA2, H2, A0); A1 = EFMA(WA3, H3, A1);
            B0 = EFMA(WB2, H2, B0); B1 = EFMA(WB3, H3, B1);
            A0 = EFMA(WA4, H4, A0); A1 = EFMA(WA5, H5, A1);
            B0 = EFMA(WB4, H4, B0); B1 = EFMA(WB5, H5, B1);
            A0 = EFMA(WA6, H6, A0); A1 = EFMA(WA7, H7, A1);
            B0 = EFMA(WB6, H6, B0); B1 = EFMA(WB7, H7, B1);
            v4f TA = A0 + A1;
            v4f TB = B0 + B1;
            parts[rowA][hh][lane] = (TA.x + TA.y) + (TA.z + TA.w);
            parts[rowB][hh][lane] = (TB.x + TB.y) + (TB.z + TB.w);
        }
        BAR_LGKM();   // all half-partials visible

        // ---- tail wave mm: gate + combine + state update ----
        if (is_tail) {
            float pm  = parts[mm * 3 + mm][0][lane] + parts[mm * 3 + mm][1][lane];
            float pc1 = parts[mm * 3 + s1][0][lane] + parts[mm * 3 + s1][1][lane];
            float pc2 = parts[mm * 3 + s2][0][lane] + parts[mm * 3 + s2][1][lane];
            float ga  = b1v
                      + (parts[9][0][lane]  + parts[9][1][lane])
                      + (parts[10][0][lane] + parts[10][1][lane])
                      + (parts[11][0][lane] + parts[11][1][lane]);

            float z = fast_tanh(ga);
            float p0 = w2r0 * z, p1 = w2r1 * z, p2 = w2r2 * z;
            DPP_RED3(p0, p1, p2);   // 64-lane sums -> lane 63
            float r0 = b2v0 + rl_f32(p0, 63);
            float r1 = b2v1 + rl_f32(p1, 63);
            float r2 = b2v2 + rl_f32(p2, 63);
            float mx  = fmaxf(r0, fmaxf(r1, r2));
            float e0  = fast_exp(r0 - mx);
            float e1  = fast_exp(r1 - mx);
            float e2  = fast_exp(r2 - mx);
            float inv = __builtin_amdgcn_rcpf(e0 + e1 + e2);
            float a1v = ((s1 == 1) ? e1 : (s1 == 2) ? e2 : e0) * inv;
            float a2v = ((s2 == 1) ? e1 : (s2 == 2) ? e2 : e0) * inv;

            float suv = xv + hbv + pm + a1v * pc1 + a2v * pc2;
            float hn  = suv * __builtin_amdgcn_rcpf(1.f + fast_exp(-suv));
            hds[nxt][mm * 64 + lane] = hn;

            if      ((t & 3) == 0) hist0 = hn;
            else if ((t & 3) == 1) hist1 = hn;
            else if ((t & 3) == 2) hist2 = hn;
            else {
                hist3 = hn;
                float* dst = hbuf + ((size_t)b * S_ + (t - 3)) * MD_ + mm * 64 + lane;
                dst[0 * MD_] = hist0; dst[1 * MD_] = hist1;
                dst[2 * MD_] = hist2; dst[3 * MD_] = hist3;
            }
        }
        BAR_LGKM();   // h_new visible
    }
}

// ---------------------------------------------------------------------------
// Kernel 3: out = LayerNorm(Ob + OW@h + x); OW row asm-pinned in registers.
// ---------------------------------------------------------------------------
__global__ __launch_bounds__(256, 2)
void k3_out(const float* __restrict__ xa, const float* __restrict__ xv,
            const float* __restrict__ xl, const float* __restrict__ hbuf,
            const float* __restrict__ OW, const float* __restrict__ Ob,
            const float* __restrict__ lng, const float* __restrict__ lnb,
            float* __restrict__ out)
{
    const int m  = blockIdx.z;
    const int b  = blockIdx.y;
    const int t0 = blockIdx.x * 128;
    const float* __restrict__ xm = (m == 0) ? xa : ((m == 1) ? xv : xl);
    const int k    = threadIdx.x;
    const int wv   = k >> 6;
    const int lane = k & 63;

    __shared__ __align__(16) float hs[4 * 64];
    __shared__ float psum[16], qsum[16];

    DECL_WSET(W, OW + (m * D_ + k) * DS_);
    const float obv = Ob[m * D_ + k];
    const float gv  = lng[m * D_ + k];
    const float bv  = lnb[m * D_ + k];

    for (int gg = 0; gg < 32; ++gg) {
        const int tb = t0 + gg * 4;
        hs[k] = hbuf[((size_t)b * S_ + tb + (k >> 6)) * MD_ + m * 64 + (k & 63)];
        __syncthreads();

        float v0, v1, v2, v3;
        {
            const v4f* h4 = reinterpret_cast<const v4f*>(&hs[0]);
            float accv; DOT64_PKV(h4, accv);
            v0 = obv + accv + xm[((size_t)b * S_ + tb + 0) * D_ + k];
        }
        {
            const v4f* h4 = reinterpret_cast<const v4f*>(&hs[64]);
            float accv; DOT64_PKV(h4, accv);
            v1 = obv + accv + xm[((size_t)b * S_ + tb + 1) * D_ + k];
        }
        {
            const v4f* h4 = reinterpret_cast<const v4f*>(&hs[128]);
            float accv; DOT64_PKV(h4, accv);
            v2 = obv + accv + xm[((size_t)b * S_ + tb + 2) * D_ + k];
        }
        {
            const v4f* h4 = reinterpret_cast<const v4f*>(&hs[192]);
            float accv; DOT64_PKV(h4, accv);
            v3 = obv + accv + xm[((size_t)b * S_ + tb + 3) * D_ + k];
        }

        float s0 = v0, s1v = v1, s2v = v2, s3 = v3;
        float q0 = v0 * v0, q1 = v1 * v1, q2 = v2 * v2, q3 = v3 * v3;
        DPP_RED4(s0, s1v, s2v, s3);
        DPP_RED4(q0, q1, q2, q3);
        if (lane == 63) {
            psum[wv * 4 + 0] = s0;  psum[wv * 4 + 1] = s1v;
            psum[wv * 4 + 2] = s2v; psum[wv * 4 + 3] = s3;
            qsum[wv * 4 + 0] = q0;  qsum[wv * 4 + 1] = q1;
            qsum[wv * 4 + 2] = q2;  qsum[wv * 4 + 3] = q3;
        }
        __syncthreads();

        const size_t obase = (size_t)m * ((size_t)B_ * S_ * D_) + ((size_t)b * S_ + tb) * D_ + k;
        {
            float ss = psum[0] + psum[4] + psum[8] + psum[12];
            float qq = qsum[0] + qsum[4] + qsum[8] + qsum[12];
            float mu = ss * (1.f / 256.f);
            float var = qq * (1.f / 256.f) - mu * mu;
            float rs = rsqrtf(var + 1e-5f);
            out[obase + 0 * D_] = (v0 - mu) * rs * gv + bv;
        }
        {
            float ss = psum[1] + psum[5] + psum[9] + psum[13];
            float qq = qsum[1] + qsum[5] + qsum[9] + qsum[13];
            float mu = ss * (1.f / 256.f);
            float var = qq * (1.f / 256.f) - mu * mu;
            float rs = rsqrtf(var + 1e-5f);
            out[obase + 1 * D_] = (v1 - mu) * rs * gv + bv;
        }
        {
            float ss = psum[2] + psum[6] + psum[10] + psum[14];
            float qq = qsum[2] + qsum[6] + qsum[10] + qsum[14];
            float mu = ss * (1.f / 256.f);
            float var = qq * (1.f / 256.f) - mu * mu;
            float rs = rsqrtf(var + 1e-5f);
            out[obase + 2 * D_] = (v2 - mu) * rs * gv + bv;
        }
        {
            float ss = psum[3] + psum[7] + psum[11] + psum[15];
            float qq = qsum[3] + qsum[7] + qsum[11] + qsum[15];
            float mu = ss * (1.f / 256.f);
            float var = qq * (1.f / 256.f) - mu * mu;
            float rs = rsqrtf(var + 1e-5f);
            out[obase + 3 * D_] = (v3 - mu) * rs * gv + bv;
        }
    }
}

extern "C" void kernel_launch(void* const* d_in, const int* in_sizes, int n_in,
                              void* d_out, int out_size, void* d_ws, size_t ws_size,
                              hipStream_t stream)
{
    const float* xa  = (const float*)d_in[0];
    const float* xv  = (const float*)d_in[1];
    const float* xl  = (const float*)d_in[2];
    const float* XW  = (const float*)d_in[3];
    const float* Xb  = (const float*)d_in[4];
    const float* HW  = (const float*)d_in[5];
    const float* Hb  = (const float*)d_in[6];
    const float* OW  = (const float*)d_in[7];
    const float* Ob  = (const float*)d_in[8];
    const float* CW  = (const float*)d_in[9];
    const float* W1  = (const float*)d_in[10];
    const float* b1  = (const float*)d_in[11];
    const float* W2  = (const float*)d_in[12];
    const float* b2  = (const float*)d_in[13];
    const float* lng = (const float*)d_in[14];
    const float* lnb = (const float*)d_in[15];
    float* out = (float*)d_out;

    float* xp = (float*)d_ws;                          // [B][S][192]
    float* hb = xp + (size_t)B_ * S_ * MD_;            // [B][S][192]

    k1_xproj<<<dim3(8, 32, 3), 256, 0, stream>>>(xa, xv, xl, XW, Xb, xp);
    k2_recur<<<dim3(32), 768, 0, stream>>>(xp, hb, HW, Hb, CW, W1, b1, W2, b2);
    k3_out  <<<dim3(8, 32, 3), 256, 0, stream>>>(xa, xv, xl, hb, OW, Ob, lng, lnb, out);
}